// Round 2
// baseline (40.274 us; speedup 1.0000x reference)
//
#include <hip/hip_runtime.h>

// RandomPool: out[b,c,i,j] = x[b, c, 2*i + s/2, 2*j + s%2], s = sel[b/8, i*56+j]
// B=32, C=128, H=W=112, side=56, K=STRIDE=2, T=8.
// ~100% of x is compulsory HBM traffic at 64B-line granularity, so stream-read
// the full 2x8 source block per thread (coalesced float4) and select in
// registers instead of issuing scattered per-pixel gathers.

#define B_ 32
#define C_ 128
#define H_ 112
#define W_ 112
#define SIDE_ 56
#define T_ 8
#define NPATCH_ (SIDE_ * SIDE_)   // 3136

__global__ __launch_bounds__(256) void randompool_kernel(
    const float* __restrict__ x,
    const int* __restrict__ sel,
    float* __restrict__ out)
{
    int idx = blockIdx.x * blockDim.x + threadIdx.x;  // one per quad of outputs
    int j4 = idx % (SIDE_ / 4);
    int v  = idx / (SIDE_ / 4);
    int i  = v % SIDE_;
    v     /= SIDE_;
    int c  = v % C_;
    int b  = v / C_;

    int clip = b >> 3;  // b / T
    const int4 s4 = *reinterpret_cast<const int4*>(sel + clip * NPATCH_ + i * SIDE_ + j4 * 4);

    // source block: rows 2i, 2i+1; cols j4*8 .. j4*8+7  (all 16B-aligned)
    const float* xp = x + (((b * C_ + c) * H_) + i * 2) * W_ + j4 * 8;
    const float4 a0 = *reinterpret_cast<const float4*>(xp);            // row0 cols 0-3
    const float4 a1 = *reinterpret_cast<const float4*>(xp + 4);        // row0 cols 4-7
    const float4 b0 = *reinterpret_cast<const float4*>(xp + W_);       // row1 cols 0-3
    const float4 b1 = *reinterpret_cast<const float4*>(xp + W_ + 4);   // row1 cols 4-7

    float4 o;
    { int s = s4.x; float t = (s & 1) ? a0.y : a0.x; float u = (s & 1) ? b0.y : b0.x; o.x = (s & 2) ? u : t; }
    { int s = s4.y; float t = (s & 1) ? a0.w : a0.z; float u = (s & 1) ? b0.w : b0.z; o.y = (s & 2) ? u : t; }
    { int s = s4.z; float t = (s & 1) ? a1.y : a1.x; float u = (s & 1) ? b1.y : b1.x; o.z = (s & 2) ? u : t; }
    { int s = s4.w; float t = (s & 1) ? a1.w : a1.z; float u = (s & 1) ? b1.w : b1.z; o.w = (s & 2) ? u : t; }

    *reinterpret_cast<float4*>(out + ((b * C_ + c) * SIDE_ + i) * SIDE_ + j4 * 4) = o;
}

extern "C" void kernel_launch(void* const* d_in, const int* in_sizes, int n_in,
                              void* d_out, int out_size, void* d_ws, size_t ws_size,
                              hipStream_t stream) {
    const float* x   = (const float*)d_in[0];
    const int*   sel = (const int*)d_in[1];
    float*       out = (float*)d_out;

    const int total_quads = B_ * C_ * SIDE_ * (SIDE_ / 4);  // 3,211,264
    const int block = 256;
    const int grid  = total_quads / block;                   // 12,544 exact
    randompool_kernel<<<grid, block, 0, stream>>>(x, sel, out);
}